// Round 11
// baseline (260.721 us; speedup 1.0000x reference)
//
#include <hip/hip_runtime.h>
#include <stdint.h>

// Problem constants
#define BB   2048
#define DIN  2048
#define UU   1024
#define KF   49
#define GM   2048         // GEMM M = batch
#define GK   3072         // GEMM K = UU + DIN
#define GN   5120         // GEMM N = 5*UU

// GEMM block geometry: 64 rows x 32 ucols x 5 gates, 256 threads (4 waves 2x2)
#define BKS  32           // K per step (96 steps)
#define SZB  14336        // bytes per LDS buffer: A 4KB + B 10KB; 2 buffers

#define NGEMM 1024        // GEMM blocks: 32 row-tiles x 32 ucol-tiles
#define NSTRM 2048        // streamer blocks (one batch-row each)

typedef __bf16  bf16x8 __attribute__((ext_vector_type(8)));
typedef float   f32x4  __attribute__((ext_vector_type(4)));

#define WAITVM0() asm volatile("s_waitcnt vmcnt(0)" ::: "memory")

static __device__ __forceinline__ unsigned short f2bf(float f) {
    union { float f; unsigned u; } x; x.f = f;
    unsigned u = x.u;
    unsigned r = (u + 0x7fffu + ((u >> 16) & 1u)) >> 16;   // RNE
    return (unsigned short)r;
}

// ---------------------------------------------------------------------------
// Kernel 1: prep = buildA (blocks [0,6144)) + buildW transpose (rest)
//   A[b][k]  = bf16([h_tm | inputs])                             [GM][GK]
//   Wt[n][k] = bf16(k<UU ? W_gates[k][n] : U_gates[k-UU][n])     [GN][GK]
// ---------------------------------------------------------------------------
__global__ void prep(const float* __restrict__ h, const float* __restrict__ x,
                     const float* __restrict__ Wg, const float* __restrict__ Ug,
                     unsigned short* __restrict__ A, unsigned short* __restrict__ Wt) {
    __shared__ float t[32][36];
    if (blockIdx.x < 6144) {
        int idx = blockIdx.x * 256 + threadIdx.x;    // one thread = 4 elems
        int b = idx / (GK / 4);
        int k = (idx % (GK / 4)) * 4;
        float4 v;
        if (k < UU) v = *(const float4*)(h + (size_t)b * UU + k);
        else        v = *(const float4*)(x + (size_t)b * DIN + (k - UU));
        ushort4 o;
        o.x = f2bf(v.x); o.y = f2bf(v.y); o.z = f2bf(v.z); o.w = f2bf(v.w);
        *(ushort4*)(A + (size_t)idx * 4) = o;
    } else {
        int bid2 = blockIdx.x - 6144;                // 32x32 transpose tiles
        int k0 = (bid2 % (GK / 32)) * 32;
        int n0 = (bid2 / (GK / 32)) * 32;
        int r  = threadIdx.x >> 3;                   // 0..31
        int cq = threadIdx.x & 7;                    // 0..7  (x4 floats)
        int k = k0 + r;
        const float* src = (k < UU) ? (Wg + (size_t)k * GN) : (Ug + (size_t)(k - UU) * GN);
        *(float4*)&t[r][cq * 4] = *(const float4*)(src + n0 + cq * 4);
        __syncthreads();
        ushort4 o;
        o.x = f2bf(t[cq * 4 + 0][r]);
        o.y = f2bf(t[cq * 4 + 1][r]);
        o.z = f2bf(t[cq * 4 + 2][r]);
        o.w = f2bf(t[cq * 4 + 3][r]);
        *(ushort4*)(Wt + (size_t)(n0 + r) * GK + k0 + cq * 4) = o;
    }
}

// ---------------------------------------------------------------------------
// Kernel 2: BLOCK-SPECIALIZED, id-interleaved 1 GEMM : 2 streamers.
//  bid%3==0 -> GEMM block gb=bid/3: tile 64 rows x 32 ucols x 5 gates,
//    2-buffer staging: issue STAGE(t+1) -> COMPUTE(t) -> vmcnt(0) -> barrier
//    (stage latency hides under compute; drain cycles absorbed by co-resident
//    streamer waves). K-part XOR-swizzle (kq = q ^ ((row>>1)&3)) permutes the
//    SOURCE within each 64B row segment: global coalescing unchanged, LDS
//    fragment reads 2-way-conflict max (was 8-way).
//  else -> streamer block: reduce one v_seq batch-row to vsum (ws).
//  ~110 VGPR + launch_bounds(256,3) -> 3 blocks/CU: each CU ~1 GEMM + 2 strm.
// ---------------------------------------------------------------------------
__global__ __launch_bounds__(256, 3) void kernel2(
        const unsigned short* __restrict__ A, const unsigned short* __restrict__ Wt,
        const float* __restrict__ m_tm, const float* __restrict__ bg,
        const float* __restrict__ v_seq, float* __restrict__ vsum,
        float* __restrict__ out) {
    __shared__ __align__(16) char lds[2 * SZB];      // 28,672 B

    const int tid = threadIdx.x;
    const int bid = blockIdx.x;
    const int sel = bid % 3;

    if (sel != 0) {
        // ---------------- streamer block: one batch-row ----------------
        const int row = (bid / 3) * 2 + (sel - 1);
        const float* vp = v_seq + (size_t)row * (KF * UU) + tid * 4;
        f32x4 s = *(const f32x4*)(vp);
#pragma unroll 8
        for (int k = 1; k < KF; ++k)
            s += *(const f32x4*)(vp + (size_t)k * UU);
        *(f32x4*)(vsum + (size_t)row * UU + tid * 4) = s;
        return;
    }

    // ---------------- GEMM block ----------------
    const int gb   = bid / 3;
    const int lane = tid & 63;
    const int wave = tid >> 6;          // 0..3
    const int wr = wave >> 1, wc = wave & 1;
    const int brow  = (gb >> 5) * 64;
    const int ucol0 = (gb & 31) * 32;

    f32x4 acc[2][5];
#pragma unroll
    for (int m = 0; m < 2; m++)
#pragma unroll
        for (int g = 0; g < 5; g++) acc[m][g] = (f32x4){0.f, 0.f, 0.f, 0.f};

    // staging: 896 chunks of 16B per K-step (A 256, B 640), 4 uniform rounds
    // (round 3 duplicated across thread halves). Source k-part swizzled:
    // LDS chunk j holds (row = j>>2, kq = (j&3) ^ ((row>>1)&3)).
    const unsigned short* src[4];
    int ldsoff[4];
#pragma unroll
    for (int r = 0; r < 4; ++r) {
        if (r == 0) {
            int j = tid;
            int row = j >> 2;
            int kq = (j & 3) ^ ((row >> 1) & 3);
            src[r] = A + (size_t)(brow + row) * GK + kq * 8;
            ldsoff[r] = j * 16;
        } else {
            int j2 = (r < 3) ? (r - 1) * 256 + tid : 512 + (tid & 127);
            int rB = j2 >> 2;                       // 0..159 = g*32 + n
            int kq = (j2 & 3) ^ ((rB >> 1) & 3);
            int g = rB >> 5, n = rB & 31;
            src[r] = Wt + ((size_t)g * UU + ucol0 + n) * GK + kq * 8;
            ldsoff[r] = 4096 + j2 * 16;
        }
    }

    // fragment read offsets (same XOR on the read side)
    int aoff[2], boff[5];
#pragma unroll
    for (int m = 0; m < 2; m++) {
        int row = wr * 32 + m * 16 + (lane & 15);
        aoff[m] = row * 64 + (((lane >> 4) ^ ((row >> 1) & 3)) * 16);
    }
#pragma unroll
    for (int g = 0; g < 5; g++) {
        int rB = g * 32 + wc * 16 + (lane & 15);
        boff[g] = 4096 + rB * 64 + (((lane >> 4) ^ ((rB >> 1) & 3)) * 16);
    }

    auto STAGE = [&](int kstep, int bufb) {
        const int ko = kstep * BKS;
#pragma unroll
        for (int r = 0; r < 4; ++r)
            __builtin_amdgcn_global_load_lds(
                (const __attribute__((address_space(1))) void*)(src[r] + ko),
                (__attribute__((address_space(3))) void*)(lds + bufb + ldsoff[r]), 16, 0, 0);
    };
    auto COMPUTE = [&](int bufb) {
        bf16x8 af[2], bfr[5];
#pragma unroll
        for (int m = 0; m < 2; m++) af[m]  = *(const bf16x8*)(lds + bufb + aoff[m]);
#pragma unroll
        for (int g = 0; g < 5; g++) bfr[g] = *(const bf16x8*)(lds + bufb + boff[g]);
#pragma unroll
        for (int m = 0; m < 2; m++)
#pragma unroll
            for (int g = 0; g < 5; g++)
                acc[m][g] = __builtin_amdgcn_mfma_f32_16x16x32_bf16(af[m], bfr[g], acc[m][g], 0, 0, 0);
    };

    // prologue: stage k-step 0 into buf0, drain, barrier
    STAGE(0, 0);
    WAITVM0();
    __builtin_amdgcn_s_barrier();
    __builtin_amdgcn_sched_barrier(0);

    int buf = 0;
    for (int t = 0; t < 96; ++t) {
        if (t < 95) STAGE(t + 1, buf ^ SZB);        // issue early
        COMPUTE(buf);                               // compute current
        if (t < 95) {
            WAITVM0();                              // wait late: t+1 landed
            __builtin_amdgcn_s_barrier();
            __builtin_amdgcn_sched_barrier(0);
        }
        buf ^= SZB;
    }

    // Epilogue: gates + cell + sentinel; out0 = ht+st (vsum added by fixup).
    const int ucol = ucol0 + wc * 16 + (lane & 15);
    const float c0 = bg[0 * UU + ucol];
    const float c1 = bg[1 * UU + ucol];
    const float c2 = bg[2 * UU + ucol];
    const float c3 = bg[3 * UU + ucol];
    const float c4 = bg[4 * UU + ucol];
    const int r0 = brow + wr * 32 + ((lane >> 4) << 2);
    float* out0 = out;
    float* out1 = out + (size_t)GM * UU;
    float* out2 = out + 2 * (size_t)GM * UU;
#pragma unroll
    for (int m = 0; m < 2; m++) {
#pragma unroll
        for (int j = 0; j < 4; j++) {
            const int row = r0 + m * 16 + j;
            const size_t idx = (size_t)row * UU + ucol;
            const float mtm = m_tm[idx];
            const float f = acc[m][0][j] + c0;
            const float i = acc[m][1][j] + c1;
            const float o = acc[m][2][j] + c2;
            const float g = acc[m][3][j] + c3;
            const float a = acc[m][4][j] + c4;
            const float ft = 1.f / (1.f + __expf(-f));
            const float it = 1.f / (1.f + __expf(-i));
            const float ot = 1.f / (1.f + __expf(-o));
            const float gt = 1.f / (1.f + __expf(-g));
            const float at = tanhf(a);
            const float mtv = mtm * ft + it * at;
            const float tm  = tanhf(mtv);
            const float ht  = ot * tm;
            const float st  = gt * tm;
            out0[idx] = ht + st;
            out1[idx] = ht;
            out2[idx] = mtv;
        }
    }
}

// ---------------------------------------------------------------------------
// Kernel 3: fixup — out0 += vsum (2M f32, f32x4 per thread)
// ---------------------------------------------------------------------------
__global__ void fixup(float* __restrict__ out0, const float* __restrict__ vsum) {
    const size_t i = ((size_t)blockIdx.x * 256 + threadIdx.x) * 4;
    f32x4 a = *(const f32x4*)(out0 + i);
    a += *(const f32x4*)(vsum + i);
    *(f32x4*)(out0 + i) = a;
}

// ---------------------------------------------------------------------------
extern "C" void kernel_launch(void* const* d_in, const int* in_sizes, int n_in,
                              void* d_out, int out_size, void* d_ws, size_t ws_size,
                              hipStream_t stream) {
    (void)in_sizes; (void)n_in; (void)out_size; (void)ws_size;
    const float* inputs  = (const float*)d_in[0];
    const float* h_tm    = (const float*)d_in[1];
    const float* m_tm    = (const float*)d_in[2];
    const float* v_seq   = (const float*)d_in[3];
    const float* W_gates = (const float*)d_in[4];
    const float* U_gates = (const float*)d_in[5];
    const float* b_gates = (const float*)d_in[6];
    // d_in[7..9] (W_z, U_z, W_h) are dead: softmax over a size-1 axis == 1.

    char* ws = (char*)d_ws;
    unsigned short* Abf = (unsigned short*)ws;                  // 2048*3072*2 = 12,582,912 B
    unsigned short* Wt  = (unsigned short*)(ws + 12582912);     // 5120*3072*2 = 31,457,280 B
    float*          vs  = (float*)(ws + 12582912 + 31457280);   // 2048*1024*4 =  8,388,608 B
    float* out = (float*)d_out;

    hipLaunchKernelGGL(prep, dim3(6144 + (GK / 32) * (GN / 32)), dim3(256), 0, stream,
                       h_tm, inputs, W_gates, U_gates, Abf, Wt);
    hipLaunchKernelGGL(kernel2, dim3(NGEMM + NSTRM), dim3(256), 0, stream,
                       Abf, Wt, m_tm, b_gates, v_seq, vs, out);
    hipLaunchKernelGGL(fixup, dim3(BB), dim3(256), 0, stream, out, vs);
}

// Round 12
// 182.712 us; speedup vs baseline: 1.4270x; 1.4270x over previous
//
#include <hip/hip_runtime.h>
#include <stdint.h>

// Problem constants
#define BB   2048
#define DIN  2048
#define UU   1024
#define KF   49
#define GM   2048         // GEMM M = batch
#define GK   3072         // GEMM K = UU + DIN
#define GN   5120         // GEMM N = 5*UU

// GEMM block geometry
#define BM    128         // batch rows per block
#define UC    64          // unit-cols per block
#define BKS   32          // K per step
#define SZBUF 28672       // bytes per LDS buffer (A 8KB + B 20KB); 3 buffers

typedef __bf16  bf16x8 __attribute__((ext_vector_type(8)));
typedef float   f32x4  __attribute__((ext_vector_type(4)));

// inline-asm HBM load: explicit FIFO position, compiler can't reorder vs waitcnt
#define VL(dst, ptr) asm volatile("global_load_dwordx4 %0, %1, off" \
                                  : "=v"(dst) : "v"(ptr) : "memory")

static __device__ __forceinline__ unsigned short f2bf(float f) {
    union { float f; unsigned u; } x; x.f = f;
    unsigned u = x.u;
    unsigned r = (u + 0x7fffu + ((u >> 16) & 1u)) >> 16;   // RNE
    return (unsigned short)r;
}

// ---------------------------------------------------------------------------
// Kernel 1: prep = buildA (blocks [0,6144)) + buildW transpose (blocks [6144,21504))
//   A[b][k]       = bf16([h_tm | inputs])                        [GM][GK]
//   Wt2[u*5+g][k] = bf16(k<UU ? W_gates[k][g*UU+u] : U_gates[k-UU][g*UU+u])
// ---------------------------------------------------------------------------
__global__ void prep(const float* __restrict__ h, const float* __restrict__ x,
                     const float* __restrict__ Wg, const float* __restrict__ Ug,
                     unsigned short* __restrict__ A, unsigned short* __restrict__ Wt) {
    __shared__ float t[32][36];
    if (blockIdx.x < 6144) {
        int idx = blockIdx.x * 256 + threadIdx.x;    // one thread = 4 elems
        int b = idx / (GK / 4);
        int k = (idx % (GK / 4)) * 4;
        float4 v;
        if (k < UU) v = *(const float4*)(h + (size_t)b * UU + k);
        else        v = *(const float4*)(x + (size_t)b * DIN + (k - UU));
        ushort4 o;
        o.x = f2bf(v.x); o.y = f2bf(v.y); o.z = f2bf(v.z); o.w = f2bf(v.w);
        *(ushort4*)(A + (size_t)idx * 4) = o;
    } else {
        int bid2 = blockIdx.x - 6144;                // 32x32 transpose tiles
        int k0 = (bid2 % (GK / 32)) * 32;
        int n0 = (bid2 / (GK / 32)) * 32;
        int r  = threadIdx.x >> 3;                   // 0..31
        int cq = threadIdx.x & 7;                    // 0..7  (x4 floats)
        int k = k0 + r;
        const float* src = (k < UU) ? (Wg + (size_t)k * GN) : (Ug + (size_t)(k - UU) * GN);
        *(float4*)&t[r][cq * 4] = *(const float4*)(src + n0 + cq * 4);
        __syncthreads();
        int n = n0 + r;                              // original col = g*UU + u
        int u = n & (UU - 1);
        int g = n >> 10;
        ushort4 o;
        o.x = f2bf(t[cq * 4 + 0][r]);
        o.y = f2bf(t[cq * 4 + 1][r]);
        o.z = f2bf(t[cq * 4 + 2][r]);
        o.w = f2bf(t[cq * 4 + 3][r]);
        *(ushort4*)(Wt + (size_t)(u * 5 + g) * GK + k0 + cq * 4) = o;
    }
}

// ---------------------------------------------------------------------------
// Kernel 2: fused 5-gate GEMM + v_seq reduction + LSTM tail.
// R6 structure (3 LDS buffers, stage t+2 ahead, vmcnt(6), raw s_barrier)
// + K-PART XOR SWIZZLE (R11-verified): LDS slot s of row r holds k-part
// s ^ ((r>>1)&3). Staging permutes the global SOURCE within each 64B row
// segment (coalescing unchanged, LDS dest linear); reads apply the same XOR.
// Fixes the 8-way bank conflict (lanes 0-15 all in banks {0,16}) down to
// 2-way (free) on both A and B fragment reads.
// ---------------------------------------------------------------------------
__global__ __launch_bounds__(512, 2) void gemm_fused(
        const unsigned short* __restrict__ A, const unsigned short* __restrict__ Wt,
        const float* __restrict__ m_tm, const float* __restrict__ bg,
        const float* __restrict__ v_seq, float* __restrict__ out) {
    __shared__ __align__(16) char lds[3 * SZBUF];   // 86016 B -> 1 block/CU

    const int tid  = threadIdx.x;
    const int lane = tid & 63;
    const int wave = tid >> 6;          // 0..7
    const int wr = wave >> 2;           // 0..1 (row half)
    const int wc = wave & 3;            // 0..3 (ucol quarter)
    const int brow  = blockIdx.y * BM;
    const int ucol0 = blockIdx.x * UC;

    f32x4 acc[4][5];
#pragma unroll
    for (int m = 0; m < 4; m++)
#pragma unroll
        for (int g = 0; g < 5; g++) acc[m][g] = (f32x4){0.f, 0.f, 0.f, 0.f};

    // staging chunk map: 1792 chunks of 16B per K-step (A 512, B 1280)
    // chunk j -> LDS row r=j>>2, slot s=j&3; SOURCE k-part = s ^ ((r>>1)&3)
    const unsigned short* src[4];
    int ldsoff[4];
#pragma unroll
    for (int t = 0; t < 4; t++) {
        if (t == 0) {
            int j = tid;
            int row = j >> 2;
            int kq = (j & 3) ^ ((row >> 1) & 3);
            src[t] = A + (size_t)(brow + row) * GK + kq * 8;
            ldsoff[t] = j * 16;
        } else {
            int j = (t < 3) ? (t - 1) * 512 + tid : 1024 + (tid & 255); // round 3 duplicated
            int rB = j >> 2;
            int kq = (j & 3) ^ ((rB >> 1) & 3);
            src[t] = Wt + (size_t)((size_t)ucol0 * 5 + rB) * GK + kq * 8;
            ldsoff[t] = 8192 + j * 16;
        }
    }

    // fragment read offsets: slot = (lane>>4) ^ ((row>>1)&3)  (same XOR)
    int aoff[4], boff[5];
#pragma unroll
    for (int m = 0; m < 4; m++) {
        int r = wr * 64 + m * 16 + (lane & 15);
        aoff[m] = r * 64 + (((lane >> 4) ^ ((r >> 1) & 3)) * 16);
    }
#pragma unroll
    for (int g = 0; g < 5; g++) {
        int rB = (wc * 16 + (lane & 15)) * 5 + g;
        boff[g] = 8192 + rB * 64 + (((lane >> 4) ^ ((rB >> 1) & 3)) * 16);
    }

    auto STAGE = [&](int kstep, int bufbase) {
        const int koff = kstep * BKS;
#pragma unroll
        for (int t = 0; t < 4; t++)
            __builtin_amdgcn_global_load_lds(
                (const __attribute__((address_space(1))) void*)(src[t] + koff),
                (__attribute__((address_space(3))) void*)(lds + bufbase + ldsoff[t]), 16, 0, 0);
    };

    auto COMPUTE = [&](int bufbase) {
        bf16x8 af[4], bfr[5];
#pragma unroll
        for (int m = 0; m < 4; m++) af[m]  = *(const bf16x8*)(lds + bufbase + aoff[m]);
#pragma unroll
        for (int g = 0; g < 5; g++) bfr[g] = *(const bf16x8*)(lds + bufbase + boff[g]);
#pragma unroll
        for (int m = 0; m < 4; m++)
#pragma unroll
            for (int g = 0; g < 5; g++)
                acc[m][g] = __builtin_amdgcn_mfma_f32_16x16x32_bf16(af[m], bfr[g], acc[m][g], 0, 0, 0);
    };

    // v_seq: thread covers rows (tid>>4)+{0,32,64,96}, float4-col tid&15
    const float* vp = v_seq + (size_t)(brow + (tid >> 4)) * (KF * UU) + ucol0 + (tid & 15) * 4;
    const size_t RG = (size_t)32 * KF * UU;
    f32x4 vacc0 = {0,0,0,0}, vacc1 = {0,0,0,0}, vacc2 = {0,0,0,0}, vacc3 = {0,0,0,0};
    f32x4 slA0, slA1, slB0, slB1;

    // prologue: S(0)->b0, V(0)->slA, S(1)->b1, V(1)->slB; wait S(0)+V(0); barrier
    STAGE(0, 0);
    VL(slA0, vp);
    VL(slA1, vp + RG);
    STAGE(1, SZBUF);
    VL(slB0, vp + 2 * RG);
    VL(slB1, vp + 3 * RG);
    asm volatile("s_waitcnt vmcnt(6)" ::: "memory");
    __builtin_amdgcn_s_barrier();
    __builtin_amdgcn_sched_barrier(0);

    int cb = 0;                                     // (t%3)*SZBUF for current t
    for (int tp = 0; tp < 47; ++tp) {
        {   // even t = 2tp: consume slA(k=tp); stage t+2; load slA<-k=tp+1
            vacc0 += slA0; vacc1 += slA1;
            int sb = cb + 2 * SZBUF; if (sb >= 3 * SZBUF) sb -= 3 * SZBUF;
            STAGE(2 * tp + 2, sb);
            VL(slA0, vp + (size_t)(tp + 1) * UU);
            VL(slA1, vp + RG + (size_t)(tp + 1) * UU);
            COMPUTE(cb);
            asm volatile("s_waitcnt vmcnt(6)" ::: "memory");
            __builtin_amdgcn_s_barrier();
            __builtin_amdgcn_sched_barrier(0);
            cb += SZBUF; if (cb >= 3 * SZBUF) cb = 0;
        }
        {   // odd t = 2tp+1: consume slB(k=tp); stage t+2; load slB<-k=tp+1
            vacc2 += slB0; vacc3 += slB1;
            int sb = cb + 2 * SZBUF; if (sb >= 3 * SZBUF) sb -= 3 * SZBUF;
            STAGE(2 * tp + 3, sb);
            VL(slB0, vp + 2 * RG + (size_t)(tp + 1) * UU);
            VL(slB1, vp + 3 * RG + (size_t)(tp + 1) * UU);
            COMPUTE(cb);
            asm volatile("s_waitcnt vmcnt(6)" ::: "memory");
            __builtin_amdgcn_s_barrier();
            __builtin_amdgcn_sched_barrier(0);
            cb += SZBUF; if (cb >= 3 * SZBUF) cb = 0;
        }
    }
    // t = 94 (cb = SZBUF): consume slA(k=47); no stage/vl; drain all
    vacc0 += slA0; vacc1 += slA1;
    COMPUTE(cb);
    asm volatile("s_waitcnt vmcnt(0)" ::: "memory");
    __builtin_amdgcn_s_barrier();
    __builtin_amdgcn_sched_barrier(0);
    cb += SZBUF; if (cb >= 3 * SZBUF) cb = 0;
    // t = 95 (cb = 2*SZBUF): consume slB(k=47)
    vacc2 += slB0; vacc3 += slB1;
    COMPUTE(cb);

    // leftover v_seq k = 48 (plain loads; pipeline drained)
    {
        const float4 w0 = *(const float4*)(vp + (size_t)48 * UU);
        const float4 w1 = *(const float4*)(vp + RG + (size_t)48 * UU);
        const float4 w2 = *(const float4*)(vp + 2 * RG + (size_t)48 * UU);
        const float4 w3 = *(const float4*)(vp + 3 * RG + (size_t)48 * UU);
        vacc0.x += w0.x; vacc0.y += w0.y; vacc0.z += w0.z; vacc0.w += w0.w;
        vacc1.x += w1.x; vacc1.y += w1.y; vacc1.z += w1.z; vacc1.w += w1.w;
        vacc2.x += w2.x; vacc2.y += w2.y; vacc2.z += w2.z; vacc2.w += w2.w;
        vacc3.x += w3.x; vacc3.y += w3.y; vacc3.z += w3.z; vacc3.w += w3.w;
    }

    // exchange v-sums via LDS: lv[128][68] floats (34.8KB; buffers free now)
    float* lv = (float*)lds;
    {
        const int xr = tid >> 4, xc = (tid & 15) * 4;
        *(f32x4*)&lv[(size_t)(xr +  0) * 68 + xc] = vacc0;
        *(f32x4*)&lv[(size_t)(xr + 32) * 68 + xc] = vacc1;
        *(f32x4*)&lv[(size_t)(xr + 64) * 68 + xc] = vacc2;
        *(f32x4*)&lv[(size_t)(xr + 96) * 68 + xc] = vacc3;
    }
    __syncthreads();

    // Epilogue: gates + cell + sentinel + ct, write 3 outputs.
    const int ucol = ucol0 + wc * 16 + (lane & 15);
    const int lcol = wc * 16 + (lane & 15);
    const float b0 = bg[0 * UU + ucol];
    const float b1 = bg[1 * UU + ucol];
    const float b2 = bg[2 * UU + ucol];
    const float b3 = bg[3 * UU + ucol];
    const float b4 = bg[4 * UU + ucol];
    const int lr0 = wr * 64 + ((lane >> 4) << 2);
    float* out0 = out;
    float* out1 = out + (size_t)GM * UU;
    float* out2 = out + 2 * (size_t)GM * UU;
#pragma unroll
    for (int m = 0; m < 4; m++) {
#pragma unroll
        for (int j = 0; j < 4; j++) {
            const int lrow = lr0 + m * 16 + j;
            const int row  = brow + lrow;
            const size_t idx = (size_t)row * UU + ucol;
            const float vs  = lv[(size_t)lrow * 68 + lcol];
            const float mtm = m_tm[idx];
            const float f = acc[m][0][j] + b0;
            const float i = acc[m][1][j] + b1;
            const float o = acc[m][2][j] + b2;
            const float g = acc[m][3][j] + b3;
            const float a = acc[m][4][j] + b4;
            const float ft = 1.f / (1.f + __expf(-f));
            const float it = 1.f / (1.f + __expf(-i));
            const float ot = 1.f / (1.f + __expf(-o));
            const float gt = 1.f / (1.f + __expf(-g));
            const float at = tanhf(a);
            const float mtv = mtm * ft + it * at;
            const float tm  = tanhf(mtv);
            const float ht  = ot * tm;
            const float st  = gt * tm;
            out0[idx] = ht + vs + st;
            out1[idx] = ht;
            out2[idx] = mtv;
        }
    }
}

// ---------------------------------------------------------------------------
extern "C" void kernel_launch(void* const* d_in, const int* in_sizes, int n_in,
                              void* d_out, int out_size, void* d_ws, size_t ws_size,
                              hipStream_t stream) {
    (void)in_sizes; (void)n_in; (void)out_size; (void)ws_size;
    const float* inputs  = (const float*)d_in[0];
    const float* h_tm    = (const float*)d_in[1];
    const float* m_tm    = (const float*)d_in[2];
    const float* v_seq   = (const float*)d_in[3];
    const float* W_gates = (const float*)d_in[4];
    const float* U_gates = (const float*)d_in[5];
    const float* b_gates = (const float*)d_in[6];
    // d_in[7..9] (W_z, U_z, W_h) are dead: softmax over a size-1 axis == 1.

    char* ws = (char*)d_ws;
    unsigned short* Abf = (unsigned short*)ws;                  // 2048*3072*2 = 12,582,912 B
    unsigned short* Wt  = (unsigned short*)(ws + 12582912);     // 5120*3072*2 = 31,457,280 B
    float* out = (float*)d_out;

    hipLaunchKernelGGL(prep, dim3(6144 + (GK / 32) * (GN / 32)), dim3(256), 0, stream,
                       h_tm, inputs, W_gates, U_gates, Abf, Wt);
    hipLaunchKernelGGL(gemm_fused, dim3(UU / UC, GM / BM), dim3(512), 0, stream,
                       Abf, Wt, m_tm, b_gates, v_seq, out);
}